// Round 7
// baseline (94.076 us; speedup 1.0000x reference)
//
#include <hip/hip_runtime.h>
#include <hip/hip_bf16.h>

#define NPTS   1024
#define HID    128
#define K_TAB  512            // lerp intervals over u = log2(d) in [U0, U1]
#define NCH    5              // 5 chunks x 128 entries = 640 >= K_TAB + 1 (halo)
#define U0f    (-10.0f)
#define U1f    (4.0f)
#define LDH    136            // padded k-stride (bf16) for h1 / W2^T tile

typedef __bf16 bf16_t;
typedef __bf16 bf16x8 __attribute__((ext_vector_type(8)));
typedef float  f32x4  __attribute__((ext_vector_type(4)));

__device__ __forceinline__ float fast_exp2(float x) {
#if __has_builtin(__builtin_amdgcn_exp2f)
    return __builtin_amdgcn_exp2f(x);
#else
    return exp2f(x);
#endif
}
__device__ __forceinline__ float fast_rcp(float x) {
#if __has_builtin(__builtin_amdgcn_rcpf)
    return __builtin_amdgcn_rcpf(x);
#else
    return 1.0f / x;
#endif
}
__device__ __forceinline__ float fast_log2(float x) {
#if __has_builtin(__builtin_amdgcn_logf)
    return __builtin_amdgcn_logf(x);
#else
    return __log2f(x);
#endif
}
__device__ __forceinline__ float fast_rsq(float x) {
#if __has_builtin(__builtin_amdgcn_rsqf)
    return __builtin_amdgcn_rsqf(x);
#else
    return rsqrtf(x);
#endif
}
// tanh(x) = 1 - 2/(e^{2x}+1). Saturates correctly at +-inf.
__device__ __forceinline__ float fast_tanh(float x) {
    float e = fast_exp2(2.8853900817779268f * x);
    return 1.0f - 2.0f * fast_rcp(e + 1.0f);
}

// Single plain kernel, no workspace. 256 blocks (1/CU), 256 threads.
// Stage 1 (per block, redundant): build mag(d) table for d = 2^u,
//   u in [U0, U1], 512 intervals + halo, via the round-2/3 MFMA pipeline
//   (table entries play the role of pairs; 128 entries per chunk).
// Stage 2: 16 i-rows per block (4 per wave), table-lerp force accumulation.
__launch_bounds__(256, 1)
__global__ void discovery_one(const float* __restrict__ pos,
                              const float* __restrict__ W1,
                              const float* __restrict__ b1,
                              const float* __restrict__ W2,
                              const float* __restrict__ b2,
                              const float* __restrict__ W3,
                              const float* __restrict__ b3,
                              float* __restrict__ out)
{
    __shared__ __align__(16) bf16_t sA[128 * LDH];        // W2^T staging, then h1 (34.8 KB)
    __shared__ __align__(16) float  tab_s[NCH * 128 + 4]; // 2.6 KB
    __shared__ float  pos_s[NPTS * 3];                    // 12 KB
    __shared__ f32x4  w1s[HID];                           // (W1[0,h],W1[1,h],W1[2,h],b1[h])
    __shared__ float  b2s[HID];
    __shared__ float  w3s[HID];

    const int t    = threadIdx.x;
    const int wave = t >> 6;
    const int lane = t & 63;
    const int ln   = lane & 15;
    const int q    = lane >> 4;

    const int b  = blockIdx.x >> 6;    // 64 blocks per batch
    const int ig = blockIdx.x & 63;    // 16 i's per block

    // ---------------- preamble ----------------
    {
        const float4* gp = (const float4*)(pos + b * NPTS * 3);
        float4* sp = (float4*)pos_s;
        for (int idx = t; idx < NPTS * 3 / 4; idx += 256) sp[idx] = gp[idx];
    }
    if (t < HID) {
        f32x4 w = { W1[t], W1[HID + t], W1[2 * HID + t], b1[t] };
        w1s[t] = w;
        b2s[t] = b2[t];
        w3s[t] = W3[t];
    }
    for (int idx = t; idx < HID * HID; idx += 256) {
        int k = idx >> 7, n = idx & 127;
        sA[n * LDH + k] = (bf16_t)W2[idx];
    }
    __syncthreads();

    // W2 B-fragments in registers (whole-kernel lifetime).
    bf16x8 wfrag[8][4];
#pragma unroll
    for (int nt = 0; nt < 8; ++nt)
#pragma unroll
        for (int ks = 0; ks < 4; ++ks)
            wfrag[nt][ks] = *(const bf16x8*)&sA[(nt * 16 + ln) * LDH + ks * 32 + q * 8];
    __syncthreads();

    const float dU  = (U1f - U0f) / (float)K_TAB;
    const float b3v = b3[0];

    // ---------------- Stage 1: table build (5 chunks x 128 entries) ----------------
    for (int c = 0; c < NCH; ++c) {
        // Phase B: h1 = tanh(feat @ W1 + b1) for entry e = c*128 + p, bf16 into sA
        {
            int p = t >> 1, half = t & 1;
            float u    = U0f + (float)(c * 128 + p) * dU;
            float d    = fast_exp2(u);
            float invc = fast_rcp(fmaxf(d, 0.01f));
            float inv2 = invc * invc;
            bf16_t* dst = &sA[p * LDH + half * 64];
#pragma unroll
            for (int g = 0; g < 8; ++g) {
                bf16x8 hb;
#pragma unroll
                for (int e = 0; e < 8; ++e) {
                    f32x4 w = w1s[half * 64 + g * 8 + e];
                    float z = fmaf(d, w[0], fmaf(invc, w[1], fmaf(inv2, w[2], w[3])));
                    hb[e] = (bf16_t)fast_tanh(z);
                }
                *(bf16x8*)(dst + g * 8) = hb;
            }
        }
        __syncthreads();

        // Phase C: h2pre = h1 @ W2 (MFMA); tab = tanh(h2pre+b2) @ W3 + b3
        {
            f32x4 zero = { 0.f, 0.f, 0.f, 0.f };
            f32x4 acc[2][8];
#pragma unroll
            for (int mt = 0; mt < 2; ++mt)
#pragma unroll
                for (int nt = 0; nt < 8; ++nt) acc[mt][nt] = zero;

            const bf16_t* a0base = &sA[(wave * 32 + ln) * LDH];
            const bf16_t* a1base = &sA[(wave * 32 + 16 + ln) * LDH];
#pragma unroll
            for (int ks = 0; ks < 4; ++ks) {
                bf16x8 a0 = *(const bf16x8*)(a0base + ks * 32 + q * 8);
                bf16x8 a1 = *(const bf16x8*)(a1base + ks * 32 + q * 8);
#pragma unroll
                for (int nt = 0; nt < 8; ++nt) {
                    acc[0][nt] = __builtin_amdgcn_mfma_f32_16x16x32_bf16(a0, wfrag[nt][ks], acc[0][nt], 0, 0, 0);
                    acc[1][nt] = __builtin_amdgcn_mfma_f32_16x16x32_bf16(a1, wfrag[nt][ks], acc[1][nt], 0, 0, 0);
                }
            }

            float pm0[4] = {0.f, 0.f, 0.f, 0.f};
            float pm1[4] = {0.f, 0.f, 0.f, 0.f};
#pragma unroll
            for (int nt = 0; nt < 8; ++nt) {
                float b2n = b2s[nt * 16 + ln];
                float w3n = w3s[nt * 16 + ln];
#pragma unroll
                for (int r = 0; r < 4; ++r) {
                    pm0[r] += fast_tanh(acc[0][nt][r] + b2n) * w3n;
                    pm1[r] += fast_tanh(acc[1][nt][r] + b2n) * w3n;
                }
            }
#pragma unroll
            for (int off = 1; off < 16; off <<= 1) {
#pragma unroll
                for (int r = 0; r < 4; ++r) {
                    pm0[r] += __shfl_xor(pm0[r], off);
                    pm1[r] += __shfl_xor(pm1[r], off);
                }
            }
            if (ln == 0) {
                // D row within 16x16 tile = q*4 + r; tiles at wave*32 (+16)
                f32x4 v0 = { pm0[0] + b3v, pm0[1] + b3v, pm0[2] + b3v, pm0[3] + b3v };
                f32x4 v1 = { pm1[0] + b3v, pm1[1] + b3v, pm1[2] + b3v, pm1[3] + b3v };
                *(f32x4*)&tab_s[c * 128 + wave * 32 + q * 4]      = v0;
                *(f32x4*)&tab_s[c * 128 + wave * 32 + 16 + q * 4] = v1;
            }
        }
        __syncthreads();
    }

    // ---------------- Stage 2: forces (4 i's per wave) ----------------
    const float S  = (float)K_TAB / (U1f - U0f);
    const int   i0 = ig * 16 + wave * 4;

    float px[4], py[4], pz[4];
#pragma unroll
    for (int v = 0; v < 4; ++v) {
        px[v] = pos_s[(i0 + v) * 3 + 0];
        py[v] = pos_s[(i0 + v) * 3 + 1];
        pz[v] = pos_s[(i0 + v) * 3 + 2];
    }
    float fx[4] = {0,0,0,0}, fy[4] = {0,0,0,0}, fz[4] = {0,0,0,0};

    for (int j = lane; j < NPTS; j += 64) {
        float qx = pos_s[j * 3 + 0], qy = pos_s[j * 3 + 1], qz = pos_s[j * 3 + 2];
#pragma unroll
        for (int v = 0; v < 4; ++v) {
            float dx = px[v] - qx, dy = py[v] - qy, dz = pz[v] - qz;
            float r2 = fmaf(dx, dx, fmaf(dy, dy, dz * dz));
            float ta = fmaf(0.5f * fast_log2(r2), S, -U0f * S);  // r2=0 -> -inf -> k=0
            float kf = fminf(fmaxf(floorf(ta), 0.0f), (float)(K_TAB - 1));
            float fr = fminf(fmaxf(ta - kf, 0.0f), 1.0f);
            int   k  = (int)kf;
            float v0 = tab_s[k], v1 = tab_s[k + 1];
            float mag = fmaf(v1 - v0, fr, v0);
            float s   = mag * fminf(fast_rsq(r2), 100.0f);       // 1/max(d,0.01)
            fx[v] = fmaf(s, dx, fx[v]);
            fy[v] = fmaf(s, dy, fy[v]);
            fz[v] = fmaf(s, dz, fz[v]);
        }
    }
#pragma unroll
    for (int off = 1; off < 64; off <<= 1) {
#pragma unroll
        for (int v = 0; v < 4; ++v) {
            fx[v] += __shfl_xor(fx[v], off);
            fy[v] += __shfl_xor(fy[v], off);
            fz[v] += __shfl_xor(fz[v], off);
        }
    }
    if (lane == 0) {
#pragma unroll
        for (int v = 0; v < 4; ++v) {
            int o = (b * NPTS + i0 + v) * 3;
            out[o + 0] = fx[v];
            out[o + 1] = fy[v];
            out[o + 2] = fz[v];
        }
    }
}

extern "C" void kernel_launch(void* const* d_in, const int* in_sizes, int n_in,
                              void* d_out, int out_size, void* d_ws, size_t ws_size,
                              hipStream_t stream) {
    const float* pos = (const float*)d_in[0];
    const float* W1  = (const float*)d_in[1];
    const float* b1  = (const float*)d_in[2];
    const float* W2  = (const float*)d_in[3];
    const float* b2  = (const float*)d_in[4];
    const float* W3  = (const float*)d_in[5];
    const float* b3  = (const float*)d_in[6];
    float* out = (float*)d_out;

    int B = (in_sizes[0] / 3) / NPTS;
    discovery_one<<<B * 64, 256, 0, stream>>>(pos, W1, b1, W2, b2, W3, b3, out);
}

// Round 8
// 78.847 us; speedup vs baseline: 1.1931x; 1.1931x over previous
//
#include <hip/hip_runtime.h>

#define NPTS   1024
#define HID    128
#define K_TAB  2048
#define U0f    (-10.0f)
#define U1f    (4.0f)

__device__ __forceinline__ float fast_exp2(float x) {
#if __has_builtin(__builtin_amdgcn_exp2f)
    return __builtin_amdgcn_exp2f(x);
#else
    return exp2f(x);
#endif
}
__device__ __forceinline__ float fast_rcp(float x) {
#if __has_builtin(__builtin_amdgcn_rcpf)
    return __builtin_amdgcn_rcpf(x);
#else
    return 1.0f / x;
#endif
}
__device__ __forceinline__ float fast_log2(float x) {
#if __has_builtin(__builtin_amdgcn_logf)
    return __builtin_amdgcn_logf(x);
#else
    return __log2f(x);
#endif
}
__device__ __forceinline__ float fast_rsq(float x) {
#if __has_builtin(__builtin_amdgcn_rsqf)
    return __builtin_amdgcn_rsqf(x);
#else
    return rsqrtf(x);
#endif
}
// tanh(x) = 1 - 2/(e^{2x}+1). Saturates correctly at +-inf.
__device__ __forceinline__ float fast_tanh(float x) {
    float e = fast_exp2(2.8853900817779268f * x);
    return 1.0f - 2.0f * fast_rcp(e + 1.0f);
}

// ---------------------------------------------------------------------------
// Kernel 1: mag(d) table, K_TAB+1 entries uniform in u = log2(d), d in
// [2^-10, 2^4]. 1025 blocks x 2 entries (block 1024 makes the halo entry).
// Thread (ee = t>>7, n = t&127): 1 layer-1 unit, then layer-2 unit n via
// 128 coalesced W2 loads, then wave-reduce. ~4 blocks/CU -> latency hidden.
// ---------------------------------------------------------------------------
__global__ __launch_bounds__(256) void build_table(const float* __restrict__ W1,
                                                   const float* __restrict__ b1,
                                                   const float* __restrict__ W2,
                                                   const float* __restrict__ b2,
                                                   const float* __restrict__ W3,
                                                   const float* __restrict__ b3,
                                                   float* __restrict__ tab)
{
    __shared__ float h1s[2][HID];
    __shared__ float red[2][HID];

    const int t = threadIdx.x, wave = t >> 6, lane = t & 63;
    const int ee = t >> 7, n = t & 127;
    const float dU = (U1f - U0f) / (float)K_TAB;
    const int e0 = blockIdx.x * 2;

    // layer 1: one (entry, unit) per thread
    {
        int e = e0 + ee; if (e > K_TAB) e = K_TAB;
        float u    = U0f + (float)e * dU;
        float d    = fast_exp2(u);
        float invc = fast_rcp(fmaxf(d, 0.01f));
        float inv2 = invc * invc;
        float z = fmaf(d, W1[n], fmaf(invc, W1[HID + n], fmaf(inv2, W1[2 * HID + n], b1[n])));
        h1s[ee][n] = fast_tanh(z);
    }
    __syncthreads();

    // layer 2: unit n of entry ee; W2 rows coalesced across n
    {
        float a = b2[n];
#pragma unroll 8
        for (int k = 0; k < HID; ++k)
            a = fmaf(h1s[ee][k], W2[k * HID + n], a);
        red[ee][n] = fast_tanh(a) * W3[n];
    }
    __syncthreads();

    // reduce 128 -> 1 per entry (waves 0,1 own entries 0,1)
    if (wave < 2) {
        float s = red[wave][lane] + red[wave][lane + 64];
#pragma unroll
        for (int off = 1; off < 64; off <<= 1) s += __shfl_xor(s, off);
        if (lane == 0 && e0 + wave <= K_TAB) tab[e0 + wave] = s + b3[0];
    }
}

// ---------------------------------------------------------------------------
// Kernel 2: forces. 256 blocks per batch, 4 i's per block (1 per wave).
// Per pair: r^2, u = 0.5*log2(r^2) (no sqrt), table lerp, f += mag*diff*rsq.
// Self-pair contributes 0 (diff = 0). Each output written exactly once.
// ---------------------------------------------------------------------------
__global__ __launch_bounds__(256) void forces_kernel(const float* __restrict__ pos,
                                                     const float* __restrict__ tab,
                                                     float* __restrict__ out)
{
    __shared__ float tab_s[K_TAB + 4];   // 8.2 KB
    __shared__ float pos_s[NPTS * 3];    // 12 KB

    const int t = threadIdx.x, wave = t >> 6, lane = t & 63;
    const int b  = blockIdx.x >> 8;      // 256 blocks per batch
    const int ig = blockIdx.x & 255;

    for (int idx = t; idx <= K_TAB; idx += 256) tab_s[idx] = tab[idx];
    {
        const float4* gp = (const float4*)(pos + b * NPTS * 3);
        float4* sp = (float4*)pos_s;
        for (int idx = t; idx < NPTS * 3 / 4; idx += 256) sp[idx] = gp[idx];
    }
    __syncthreads();

    const int   i  = ig * 4 + wave;
    const float px = pos_s[i * 3 + 0], py = pos_s[i * 3 + 1], pz = pos_s[i * 3 + 2];
    const float S  = (float)K_TAB / (U1f - U0f);

    float fx = 0.f, fy = 0.f, fz = 0.f;
#pragma unroll 4
    for (int j = lane; j < NPTS; j += 64) {
        float dx = px - pos_s[j * 3 + 0];
        float dy = py - pos_s[j * 3 + 1];
        float dz = pz - pos_s[j * 3 + 2];
        float r2 = fmaf(dx, dx, fmaf(dy, dy, dz * dz));
        float ta = fmaf(0.5f * fast_log2(r2), S, -U0f * S);   // r2=0 -> -inf -> k=0
        float kf = fminf(fmaxf(floorf(ta), 0.0f), (float)(K_TAB - 1));
        float fr = fminf(fmaxf(ta - kf, 0.0f), 1.0f);
        int   k  = (int)kf;
        float v0 = tab_s[k], v1 = tab_s[k + 1];
        float mag = fmaf(v1 - v0, fr, v0);
        float s   = mag * fminf(fast_rsq(r2), 100.0f);        // 1/max(d,0.01); rsq(0)=inf->100
        fx = fmaf(s, dx, fx);
        fy = fmaf(s, dy, fy);
        fz = fmaf(s, dz, fz);
    }
#pragma unroll
    for (int off = 1; off < 64; off <<= 1) {
        fx += __shfl_xor(fx, off);
        fy += __shfl_xor(fy, off);
        fz += __shfl_xor(fz, off);
    }
    if (lane == 0) {
        int o = (b * NPTS + i) * 3;
        out[o + 0] = fx;
        out[o + 1] = fy;
        out[o + 2] = fz;
    }
}

extern "C" void kernel_launch(void* const* d_in, const int* in_sizes, int n_in,
                              void* d_out, int out_size, void* d_ws, size_t ws_size,
                              hipStream_t stream) {
    const float* pos = (const float*)d_in[0];
    const float* W1  = (const float*)d_in[1];
    const float* b1  = (const float*)d_in[2];
    const float* W2  = (const float*)d_in[3];
    const float* b2  = (const float*)d_in[4];
    const float* W3  = (const float*)d_in[5];
    const float* b3  = (const float*)d_in[6];
    float* out = (float*)d_out;
    float* tab = (float*)d_ws;   // (K_TAB+1) floats

    int B = (in_sizes[0] / 3) / NPTS;
    build_table<<<K_TAB / 2 + 1, 256, 0, stream>>>(W1, b1, W2, b2, W3, b3, tab);
    forces_kernel<<<B * 256, 256, 0, stream>>>(pos, tab, out);
}